// Round 11
// baseline (2249.473 us; speedup 1.0000x reference)
//
#include <hip/hip_runtime.h>
#include <stdint.h>

// SkipGRU: T=384, B=48, C=H=256, L=2.
// r11 = r10 fused cross-layer pipeline + two fixes:
//  (1) C-pacing restored: r10's C replaced A's mid-phase-2 GI1 HBM loads
//      (~900cy, drained by B2's vmcnt(0) -> symmetric pair delay -> zero-retry
//      pair polls; the r8/r9 lesson) with ~400cy LLC ring polls -> C's pair
//      exchange stormed (FETCH 51->177MB) -> C step ~5us -> pipeline chained
//      instead of overlapped (4.95us/step = stepA+stepB+stepC). C now ALSO
//      issues the same 3 GI1 HBM loads in the same slot, kept alive across B2
//      by an asm(""::"v") at next step top (else DCE'd), reproducing r9's
//      drain length exactly. Zero extra registers (reuses gir/giz/gin).
//  (2) B balanced: 48 WGs x 2 batches (was 16 x 6 = 1152 FMA/lane/step, 3x an
//      A/C stage); now 384 FMA/lane/step. Grid 240 <= 256: all resident.
// Roles: A(96)=layer-1 rec pairs (r9 verbatim + y1 ring publish, no Y0);
// B(48)=gi2 producers (half W_ih2 in 192 regs, 2 batches); C(96)=layer-2 rec
// pairs (gi2 from 16-deep tagged ring, pacing per (1)), writes OUTy/HS/TU.
// Deadlock-freedom: all blocks resident; mutual waits only within pairs
// (r2-verified tagged protocol); A->B->C forward-only; ring reuse guarded by
// progress counters (D=16), acyclic. Tags/progress zeroed per launch.

#define T_STEPS 384
typedef unsigned long long u64t;

__device__ __forceinline__ float sigm_(float x) { return 1.f / (1.f + __expf(-x)); }
__device__ __forceinline__ float tanh_(float x) {
    float ax = fabsf(x);
    float e  = __expf(-2.f * ax);
    float r  = (1.f - e) / (1.f + e);
    return copysignf(r, x);
}

// ---------------------------------------------------------------------------
// GEMM1: O[m][n] = sum_k X[m][k]*W[n][k] + B[n]; M=18432, N=768, K=256.
// (unchanged)
// ---------------------------------------------------------------------------
__global__ __launch_bounds__(256, 2) void gemm_nt(const float* __restrict__ X,
                                                  const float* __restrict__ W,
                                                  const float* __restrict__ B,
                                                  float* __restrict__ O)
{
    __shared__ float As[32 * 140];
    __shared__ float Bs[32 * 68];

    const int tid = threadIdx.x;
    const int tx  = tid & 15;
    const int ty  = tid >> 4;
    const int n0  = blockIdx.x * 64;
    const int m0  = blockIdx.y * 128;

    float acc[8][4];
#pragma unroll
    for (int i = 0; i < 8; ++i)
#pragma unroll
        for (int j = 0; j < 4; ++j) acc[i][j] = 0.f;

    const float4 bias4 = *reinterpret_cast<const float4*>(B + n0 + tx * 4);

    for (int kc = 0; kc < 8; ++kc) {
        const int k0 = kc * 32;
        float4 a[4], bb[2];
#pragma unroll
        for (int j = 0; j < 4; ++j) {
            int f = tid + 256 * j, r = f >> 3, cq = f & 7;
            a[j] = *reinterpret_cast<const float4*>(X + (size_t)(m0 + r) * 256 + k0 + cq * 4);
        }
#pragma unroll
        for (int j = 0; j < 2; ++j) {
            int f = tid + 256 * j, r = f >> 3, cq = f & 7;
            bb[j] = *reinterpret_cast<const float4*>(W + (size_t)(n0 + r) * 256 + k0 + cq * 4);
        }
        __syncthreads();
#pragma unroll
        for (int j = 0; j < 4; ++j) {
            int f = tid + 256 * j, r = f >> 3, cq = f & 7;
            As[(cq * 4 + 0) * 140 + r] = a[j].x;
            As[(cq * 4 + 1) * 140 + r] = a[j].y;
            As[(cq * 4 + 2) * 140 + r] = a[j].z;
            As[(cq * 4 + 3) * 140 + r] = a[j].w;
        }
#pragma unroll
        for (int j = 0; j < 2; ++j) {
            int f = tid + 256 * j, r = f >> 3, cq = f & 7;
            Bs[(cq * 4 + 0) * 68 + r] = bb[j].x;
            Bs[(cq * 4 + 1) * 68 + r] = bb[j].y;
            Bs[(cq * 4 + 2) * 68 + r] = bb[j].z;
            Bs[(cq * 4 + 3) * 68 + r] = bb[j].w;
        }
        __syncthreads();
#pragma unroll 8
        for (int kk = 0; kk < 32; ++kk) {
            float4 av0 = *reinterpret_cast<const float4*>(As + kk * 140 + ty * 8);
            float4 av1 = *reinterpret_cast<const float4*>(As + kk * 140 + ty * 8 + 4);
            float4 bv  = *reinterpret_cast<const float4*>(Bs + kk * 68 + tx * 4);
            float am[8] = {av0.x, av0.y, av0.z, av0.w, av1.x, av1.y, av1.z, av1.w};
            float bn[4] = {bv.x, bv.y, bv.z, bv.w};
#pragma unroll
            for (int i = 0; i < 8; ++i)
#pragma unroll
                for (int j = 0; j < 4; ++j) acc[i][j] = fmaf(am[i], bn[j], acc[i][j]);
        }
    }
#pragma unroll
    for (int i = 0; i < 8; ++i) {
        int row = m0 + ty * 8 + i;
        float4 o;
        o.x = acc[i][0] + bias4.x;
        o.y = acc[i][1] + bias4.y;
        o.z = acc[i][2] + bias4.z;
        o.w = acc[i][3] + bias4.w;
        *reinterpret_cast<float4*>(O + (size_t)row * 768 + n0 + tx * 4) = o;
    }
}

// ---------------------------------------------------------------------------
__global__ __launch_bounds__(512, 2) void fused_pipe(
    const float* __restrict__ GI1,
    const float* __restrict__ wih2, const float* __restrict__ bih2,
    const float* __restrict__ whh1, const float* __restrict__ bhh1,
    const float* __restrict__ whh2, const float* __restrict__ bhh2,
    const float* __restrict__ lw1, const float* __restrict__ lb1,
    const float* __restrict__ lw2, const float* __restrict__ lb2,
    const float* __restrict__ hid1, const float* __restrict__ hid2,
    u64t* XH1, u64t* PD1, u64t* XH2, u64t* PD2,
    u64t* Y1X, u64t* GI2X, unsigned int* BPROG, unsigned int* CPROG,
    float* __restrict__ OUTy, float* __restrict__ HS, float* __restrict__ TU)
{
    __shared__ float hbuf[2112];   // A/C: 2 parities x 4 copies x 264
    __shared__ float pdw[2][8];
    __shared__ float ybuf[2112];   // B: 2 batches x (4 copies x 264)

    const int tid  = threadIdx.x;
    const int lane = tid & 63;
    const int w    = tid >> 6;
    const int g    = lane & 15;
    const int s    = lane >> 4;
    const int blk  = blockIdx.x;

    if (blk < 192) {
        // ================= roles A (blk<96) and C (96..191): rec pair ======
        const bool isA = (blk < 96);
        const int rb   = isA ? blk : (blk - 96);
        const int b    = rb % 48;
        const int p    = rb / 48;
        const int q    = 1 - p;
        const int cb   = w * 16 + g;
        const int c    = p * 128 + cb;

        const float* whh = isA ? whh1 : whh2;
        const float* bhh = isA ? bhh1 : bhh2;
        const float* lwl = isA ? lw1 : lw2;
        const float* lbl = isA ? lb1 : lb2;
        const float* hid = isA ? hid1 : hid2;
        u64t* XHb = (isA ? XH1 : XH2) + b * 512;
        u64t* PDb = (isA ? PD1 : PD2) + b * 4;

        float4 WrO[8], WzO[8], WnO[8], WrP[8], WzP[8], WnP[8];
        {
            const size_t rR = (size_t)c * 256;
            const size_t rZ = (size_t)(256 + c) * 256;
            const size_t rN = (size_t)(512 + c) * 256;
            const int ko = p * 128 + s * 32;
            const int kq = q * 128 + s * 32;
            const float4* a  = reinterpret_cast<const float4*>(whh + rR + ko);
            const float4* bv = reinterpret_cast<const float4*>(whh + rZ + ko);
            const float4* cv = reinterpret_cast<const float4*>(whh + rN + ko);
            const float4* d4 = reinterpret_cast<const float4*>(whh + rR + kq);
            const float4* e4 = reinterpret_cast<const float4*>(whh + rZ + kq);
            const float4* f4 = reinterpret_cast<const float4*>(whh + rN + kq);
#pragma unroll
            for (int i = 0; i < 8; ++i) {
                WrO[i] = a[i];  WzO[i] = bv[i]; WnO[i] = cv[i];
                WrP[i] = d4[i]; WzP[i] = e4[i]; WnP[i] = f4[i];
            }
        }
        const float bhr = bhh[c], bhz = bhh[256 + c], bhn = bhh[512 + c];
        const float lwc = lwl[c];
        const float lbv = lbl[0];

        if (tid < 256) {
            float v = hid[tid];
            hbuf[tid] = v; hbuf[264 + tid] = v; hbuf[528 + tid] = v; hbuf[792 + tid] = v;
        }
        __syncthreads();

        // gi(0): A reads GEMM1 output; C issues ring polls (checked at t=0 top)
        float gir = 0.f, giz = 0.f, gin = 0.f;
        u64t pkr = 0, pkz = 0, pkn = 0;
        if (isA) {
            const size_t g0 = (size_t)b * 768 + c;
            gir = GI1[g0]; giz = GI1[g0 + 256]; gin = GI1[g0 + 512];
        } else {
            const u64t* g0 = GI2X + ((size_t)b * 16) * 768 + c;
            pkr = __hip_atomic_load(g0,       __ATOMIC_RELAXED, __HIP_MEMORY_SCOPE_AGENT);
            pkz = __hip_atomic_load(g0 + 256, __ATOMIC_RELAXED, __HIP_MEMORY_SCOPE_AGENT);
            pkn = __hip_atomic_load(g0 + 512, __ATOMIC_RELAXED, __HIP_MEMORY_SCOPE_AGENT);
        }

        float sAr, sAz, sAn;
        {
            float ar = 0.f, az = 0.f, an = 0.f;
            const float4* ho = reinterpret_cast<const float4*>(hbuf + s * 264 + p * 128 + s * 32);
            const float4* hq = reinterpret_cast<const float4*>(hbuf + s * 264 + q * 128 + s * 32);
#pragma unroll
            for (int i = 0; i < 8; ++i) {
                float4 hv = ho[i];
                ar = fmaf(WrO[i].x, hv.x, ar); ar = fmaf(WrO[i].y, hv.y, ar);
                ar = fmaf(WrO[i].z, hv.z, ar); ar = fmaf(WrO[i].w, hv.w, ar);
                az = fmaf(WzO[i].x, hv.x, az); az = fmaf(WzO[i].y, hv.y, az);
                az = fmaf(WzO[i].z, hv.z, az); az = fmaf(WzO[i].w, hv.w, az);
                an = fmaf(WnO[i].x, hv.x, an); an = fmaf(WnO[i].y, hv.y, an);
                an = fmaf(WnO[i].z, hv.z, an); an = fmaf(WnO[i].w, hv.w, an);
            }
#pragma unroll
            for (int i = 0; i < 8; ++i) {
                float4 hv = hq[i];
                ar = fmaf(WrP[i].x, hv.x, ar); ar = fmaf(WrP[i].y, hv.y, ar);
                ar = fmaf(WrP[i].z, hv.z, ar); ar = fmaf(WrP[i].w, hv.w, ar);
                az = fmaf(WzP[i].x, hv.x, az); az = fmaf(WzP[i].y, hv.y, az);
                az = fmaf(WzP[i].z, hv.z, az); az = fmaf(WzP[i].w, hv.w, az);
                an = fmaf(WnP[i].x, hv.x, an); an = fmaf(WnP[i].y, hv.y, an);
                an = fmaf(WnP[i].z, hv.z, an); an = fmaf(WnP[i].w, hv.w, an);
            }
            ar += __shfl_xor(ar, 16); ar += __shfl_xor(ar, 32);
            az += __shfl_xor(az, 16); az += __shfl_xor(az, 32);
            an += __shfl_xor(an, 16); an += __shfl_xor(an, 32);
            sAr = ar; sAz = az; sAn = an;
        }

        float* hsout = isA ? HS : (HS + 12288);
        float* tubase = TU + (isA ? 0 : 384);
        u64t*  Y1b = Y1X + (size_t)b * 16 * 256;

        float u = 1.f, d = 0.f;
        bool  skip = false;
        int   ns = 0, hp = 0, bcap = 16;
        // C pacing carriers (loaded each step from GI1, consumed by asm below)
        float pcr = 0.f, pcz = 0.f, pcn = 0.f;

        for (int t = 0; t < T_STEPS; ++t) {
            // C pacing keep-alive: forces last step's GI1 loads to live across
            // B2 so its vmcnt(0) drain includes their ~900cy (r9's self-clock).
            if (!isA) asm volatile("" :: "v"(pcr), "v"(pcz), "v"(pcn));

            const float bu  = rintf(u);        // jnp.round == RNE
            const float obu = 1.f - bu;
            const int tp = (t < T_STEPS - 1) ? t + 1 : t;
            const size_t gpb = ((size_t)tp * 48 + b) * 768 + c;
            const u64t* gnext = GI2X + ((size_t)b * 16 + (tp & 15)) * 768 + c; // C only
            const size_t yrow = ((size_t)t * 48 + b) * 256;

            // A: ring backpressure vs B (uniform; rare refresh)
            if (isA && t >= bcap) {
                unsigned int m;
                do {
                    unsigned int p0 = __hip_atomic_load(BPROG + b * 2,     __ATOMIC_RELAXED, __HIP_MEMORY_SCOPE_AGENT);
                    unsigned int p1 = __hip_atomic_load(BPROG + b * 2 + 1, __ATOMIC_RELAXED, __HIP_MEMORY_SCOPE_AGENT);
                    m = p0 < p1 ? p0 : p1;
                } while ((int)m < t - 15);
                bcap = (int)m + 16;
            }
            u64t* yslot = Y1b + (size_t)(t & 15) * 256;

            if (skip) {
                float* hb = hbuf + hp * 1056;
                float hcv = hb[s * 264 + c];
                float nh  = hcv * obu;
                if (bu != 0.f) hb[s * 264 + c] = nh;
                if (s == 0) {
                    if (isA) {
                        u64t pk = ((u64t)(unsigned)(t + 1) << 32) | (u64t)__float_as_uint(nh);
                        __hip_atomic_store(yslot + c, pk, __ATOMIC_RELAXED, __HIP_MEMORY_SCOPE_AGENT);
                    }
                } else if (s == 1) {
                    if (!isA) OUTy[yrow + c] = nh;
                    if (t == T_STEPS - 1) hsout[b * 256 + c] = nh;
                }
                if (bu != 0.f) { sAr = 0.f; sAz = 0.f; sAn = 0.f; }
                if (p == 0 && tid == 0) tubase[b * 768 + t] = bu;
                if (!isA && tid == 0)
                    __hip_atomic_store(CPROG + b * 2 + p, (unsigned)(t + 1), __ATOMIC_RELAXED, __HIP_MEMORY_SCOPE_AGENT);
                // prefetch slot: A real gi(t+1); C ring polls + GI1 pacing loads
                float pr = 0.f, pz = 0.f, pn = 0.f;
                if (isA) { pr = GI1[gpb]; pz = GI1[gpb + 256]; pn = GI1[gpb + 512]; }
                else {
                    pkr = __hip_atomic_load(gnext,       __ATOMIC_RELAXED, __HIP_MEMORY_SCOPE_AGENT);
                    pkz = __hip_atomic_load(gnext + 256, __ATOMIC_RELAXED, __HIP_MEMORY_SCOPE_AGENT);
                    pkn = __hip_atomic_load(gnext + 512, __ATOMIC_RELAXED, __HIP_MEMORY_SCOPE_AGENT);
                    pcr = GI1[gpb]; pcz = GI1[gpb + 256]; pcn = GI1[gpb + 512];
                }
                u    = fminf(fmaxf(u + d, 0.f), 1.f) * obu;
                skip = (u < 0.5f);
                __syncthreads();
                if (isA) { gir = pr; giz = pz; gin = pn; }
            } else {
                const int sl = ns & 1;
                const unsigned int tag = (unsigned)ns + 1u;

                if (!isA) {
                    // complete gi2(t) polls (zero retries once B leads C)
                    const u64t* gcur = GI2X + ((size_t)b * 16 + (t & 15)) * 768 + c;
                    const unsigned int wt = (unsigned)(t + 1);
                    while ((unsigned)(pkr >> 32) < wt)
                        pkr = __hip_atomic_load(gcur,       __ATOMIC_RELAXED, __HIP_MEMORY_SCOPE_AGENT);
                    while ((unsigned)(pkz >> 32) < wt)
                        pkz = __hip_atomic_load(gcur + 256, __ATOMIC_RELAXED, __HIP_MEMORY_SCOPE_AGENT);
                    while ((unsigned)(pkn >> 32) < wt)
                        pkn = __hip_atomic_load(gcur + 512, __ATOMIC_RELAXED, __HIP_MEMORY_SCOPE_AGENT);
                    gir = __uint_as_float((unsigned)pkr);
                    giz = __uint_as_float((unsigned)pkz);
                    gin = __uint_as_float((unsigned)pkn);
                }

                float hcv = hbuf[hp * 1056 + s * 264 + c];
                float rr  = sigm_(gir + sAr + bhr);
                float zz  = sigm_(giz + sAz + bhz);
                float tn  = tanh_(gin + rr * (sAn + bhn));
                float nh  = ((1.f - zz) * tn + zz * hcv) * bu;
                float pdv = nh * lwc;

                float* hbn = hbuf + (hp ^ 1) * 1056;
                hbn[s * 264 + c] = nh;
                if (s == 0) {
                    u64t pkx = ((u64t)tag << 32) | (u64t)__float_as_uint(nh);
                    __hip_atomic_store(XHb + sl * 256 + c, pkx, __ATOMIC_RELAXED, __HIP_MEMORY_SCOPE_AGENT);
                    if (isA) {
                        u64t pky = ((u64t)(unsigned)(t + 1) << 32) | (u64t)__float_as_uint(nh);
                        __hip_atomic_store(yslot + c, pky, __ATOMIC_RELAXED, __HIP_MEMORY_SCOPE_AGENT);
                    }
                } else if (s == 1) {
                    if (!isA) OUTy[yrow + c] = nh;
                    if (t == T_STEPS - 1) hsout[b * 256 + c] = nh;
                }
                pdv += __shfl_xor(pdv, 1);  pdv += __shfl_xor(pdv, 2);  pdv += __shfl_xor(pdv, 4);
                pdv += __shfl_xor(pdv, 8);  pdv += __shfl_xor(pdv, 16); pdv += __shfl_xor(pdv, 32);
                pdv *= 0.25f;
                if (lane == 0) pdw[sl][w] = pdv;
                if (p == 0 && tid == 0) tubase[b * 768 + t] = bu;
                if (!isA && tid == 0)
                    __hip_atomic_store(CPROG + b * 2 + p, (unsigned)(t + 1), __ATOMIC_RELAXED, __HIP_MEMORY_SCOPE_AGENT);
                __syncthreads();  // B1

                float ownpd = ((pdw[sl][0] + pdw[sl][1]) + (pdw[sl][2] + pdw[sl][3]))
                            + ((pdw[sl][4] + pdw[sl][5]) + (pdw[sl][6] + pdw[sl][7]));
                if (tid == 0) {
                    u64t pkp = ((u64t)tag << 32) | (u64t)__float_as_uint(ownpd);
                    __hip_atomic_store(PDb + sl * 2 + p, pkp, __ATOMIC_RELAXED, __HIP_MEMORY_SCOPE_AGENT);
                }
                u64t pk0 = __hip_atomic_load(XHb + sl * 256 + q * 128 + cb, __ATOMIC_RELAXED, __HIP_MEMORY_SCOPE_AGENT);
                // mid-phase-2 prefetch slot (pacing position): A real GI1;
                // C ring polls for t+1 PLUS the same GI1 loads as pacing
                float pr = 0.f, pz = 0.f, pn = 0.f;
                if (isA) { pr = GI1[gpb]; pz = GI1[gpb + 256]; pn = GI1[gpb + 512]; }
                else {
                    pkr = __hip_atomic_load(gnext,       __ATOMIC_RELAXED, __HIP_MEMORY_SCOPE_AGENT);
                    pkz = __hip_atomic_load(gnext + 256, __ATOMIC_RELAXED, __HIP_MEMORY_SCOPE_AGENT);
                    pkn = __hip_atomic_load(gnext + 512, __ATOMIC_RELAXED, __HIP_MEMORY_SCOPE_AGENT);
                    pcr = GI1[gpb]; pcz = GI1[gpb + 256]; pcn = GI1[gpb + 512];
                }

                float ar = 0.f, az = 0.f, an = 0.f;
                {
                    const float4* ho = reinterpret_cast<const float4*>(hbn + s * 264 + p * 128 + s * 32);
#pragma unroll
                    for (int i = 0; i < 8; ++i) {
                        float4 hv = ho[i];
                        ar = fmaf(WrO[i].x, hv.x, ar); ar = fmaf(WrO[i].y, hv.y, ar);
                        ar = fmaf(WrO[i].z, hv.z, ar); ar = fmaf(WrO[i].w, hv.w, ar);
                        az = fmaf(WzO[i].x, hv.x, az); az = fmaf(WzO[i].y, hv.y, az);
                        az = fmaf(WzO[i].z, hv.z, az); az = fmaf(WzO[i].w, hv.w, az);
                        an = fmaf(WnO[i].x, hv.x, an); an = fmaf(WnO[i].y, hv.y, an);
                        an = fmaf(WnO[i].z, hv.z, an); an = fmaf(WnO[i].w, hv.w, an);
                    }
                }
                {
                    const int qc = q * 128 + cb;
                    const u64t* slp = XHb + sl * 256 + qc;
                    while ((unsigned)(pk0 >> 32) < tag)
                        pk0 = __hip_atomic_load(slp, __ATOMIC_RELAXED, __HIP_MEMORY_SCOPE_AGENT);
                    hbn[s * 264 + qc] = __uint_as_float((unsigned)pk0);
                }
                __syncthreads();  // B2 (drains C's GI1 pacing loads too)

                u64t pkq = __hip_atomic_load(PDb + sl * 2 + q, __ATOMIC_RELAXED, __HIP_MEMORY_SCOPE_AGENT);
                {
                    const float4* hq = reinterpret_cast<const float4*>(hbn + s * 264 + q * 128 + s * 32);
#pragma unroll
                    for (int i = 0; i < 8; ++i) {
                        float4 hv = hq[i];
                        ar = fmaf(WrP[i].x, hv.x, ar); ar = fmaf(WrP[i].y, hv.y, ar);
                        ar = fmaf(WrP[i].z, hv.z, ar); ar = fmaf(WrP[i].w, hv.w, ar);
                        az = fmaf(WzP[i].x, hv.x, az); az = fmaf(WzP[i].y, hv.y, az);
                        az = fmaf(WzP[i].z, hv.z, az); az = fmaf(WzP[i].w, hv.w, az);
                        an = fmaf(WnP[i].x, hv.x, an); an = fmaf(WnP[i].y, hv.y, an);
                        an = fmaf(WnP[i].z, hv.z, an); an = fmaf(WnP[i].w, hv.w, an);
                    }
                }
                ar += __shfl_xor(ar, 16); ar += __shfl_xor(ar, 32);
                az += __shfl_xor(az, 16); az += __shfl_xor(az, 32);
                an += __shfl_xor(an, 16); an += __shfl_xor(an, 32);
                sAr = ar; sAz = az; sAn = an;

                while ((unsigned)(pkq >> 32) < tag)
                    pkq = __hip_atomic_load(PDb + sl * 2 + q, __ATOMIC_RELAXED, __HIP_MEMORY_SCOPE_AGENT);
                const float pdq = __uint_as_float((unsigned)pkq);

                float dns = sigm_((ownpd + pdq) + lbv);  // commutative -> lockstep
                u = dns * bu; d = dns;
                skip = (u < 0.5f);
                ns++; hp ^= 1;
                if (isA) { gir = pr; giz = pz; gin = pn; }
            }
        }
    } else {
        // ================= role B: gi2 producer (2 batches/WG) =============
        const int j   = blk - 192;       // 0..47
        const int hf  = j & 1;
        const int b0  = (j >> 1) * 2;    // batches b0, b0+1
        const int cb2 = w * 16 + g;
        const int c2  = hf * 128 + cb2;

        float4 Wr[16], Wz[16], Wn[16];
        {
            const float4* r4 = reinterpret_cast<const float4*>(wih2 + (size_t)c2 * 256 + s * 64);
            const float4* z4 = reinterpret_cast<const float4*>(wih2 + (size_t)(256 + c2) * 256 + s * 64);
            const float4* n4 = reinterpret_cast<const float4*>(wih2 + (size_t)(512 + c2) * 256 + s * 64);
#pragma unroll
            for (int i = 0; i < 16; ++i) { Wr[i] = r4[i]; Wz[i] = z4[i]; Wn[i] = n4[i]; }
        }
        const float bR = bih2[c2], bZ = bih2[256 + c2], bN = bih2[512 + c2];

        int ccap[2] = {16, 16};
        const int bb0 = tid >> 8;        // 0..1
        const int co0 = tid & 255;

        for (int t = 0; t < T_STEPS; ++t) {
            const int slot = t & 15;
            const unsigned int wt = (unsigned)(t + 1);
            const u64t* a0 = Y1X + ((size_t)(b0 + bb0) * 16 + slot) * 256 + co0;
            u64t v0 = __hip_atomic_load(a0, __ATOMIC_RELAXED, __HIP_MEMORY_SCOPE_AGENT);
            while ((unsigned)(v0 >> 32) < wt)
                v0 = __hip_atomic_load(a0, __ATOMIC_RELAXED, __HIP_MEMORY_SCOPE_AGENT);
            {
                float v = __uint_as_float((unsigned)v0); float* yb = ybuf + bb0 * 1056;
                yb[co0] = v; yb[264 + co0] = v; yb[528 + co0] = v; yb[792 + co0] = v;
            }
            __syncthreads();
            if (tid < 2)
                __hip_atomic_store(BPROG + (b0 + tid) * 2 + hf, wt, __ATOMIC_RELAXED, __HIP_MEMORY_SCOPE_AGENT);
#pragma unroll
            for (int bb = 0; bb < 2; ++bb) {
                if (t >= ccap[bb]) {   // ring backpressure vs C (uniform, rare)
                    unsigned int m;
                    do {
                        m = __hip_atomic_load(CPROG + (b0 + bb) * 2 + hf, __ATOMIC_RELAXED, __HIP_MEMORY_SCOPE_AGENT);
                    } while ((int)m < t - 15);
                    ccap[bb] = (int)m + 16;
                }
                float ar = 0.f, az = 0.f, an = 0.f;
                const float4* yv = reinterpret_cast<const float4*>(ybuf + bb * 1056 + s * 328);
#pragma unroll
                for (int i = 0; i < 16; ++i) {
                    float4 hv = yv[i];
                    ar = fmaf(Wr[i].x, hv.x, ar); ar = fmaf(Wr[i].y, hv.y, ar);
                    ar = fmaf(Wr[i].z, hv.z, ar); ar = fmaf(Wr[i].w, hv.w, ar);
                    az = fmaf(Wz[i].x, hv.x, az); az = fmaf(Wz[i].y, hv.y, az);
                    az = fmaf(Wz[i].z, hv.z, az); az = fmaf(Wz[i].w, hv.w, az);
                    an = fmaf(Wn[i].x, hv.x, an); an = fmaf(Wn[i].y, hv.y, an);
                    an = fmaf(Wn[i].z, hv.z, an); an = fmaf(Wn[i].w, hv.w, an);
                }
                ar += __shfl_xor(ar, 16); ar += __shfl_xor(ar, 32);
                az += __shfl_xor(az, 16); az += __shfl_xor(az, 32);
                an += __shfl_xor(an, 16); an += __shfl_xor(an, 32);
                ar += bR; az += bZ; an += bN;
                if (s < 3) {
                    float v = (s == 0) ? ar : ((s == 1) ? az : an);
                    u64t pk = ((u64t)wt << 32) | (u64t)__float_as_uint(v);
                    __hip_atomic_store(GI2X + ((size_t)(b0 + bb) * 16 + slot) * 768 + s * 256 + c2,
                                       pk, __ATOMIC_RELAXED, __HIP_MEMORY_SCOPE_AGENT);
                }
            }
            __syncthreads();  // ybuf reuse guard
        }
    }
}

// ---------------------------------------------------------------------------
extern "C" void kernel_launch(void* const* d_in, const int* in_sizes, int n_in,
                              void* d_out, int out_size, void* d_ws, size_t ws_size,
                              hipStream_t stream)
{
    const float* x   = (const float*)d_in[0];  // (384,48,256)
    const float* hid = (const float*)d_in[1];  // (2,1,256)
    const float* wih = (const float*)d_in[2];  // (2,768,256)
    const float* whh = (const float*)d_in[3];  // (2,768,256)
    const float* bih = (const float*)d_in[4];  // (2,768)
    const float* bhh = (const float*)d_in[5];  // (2,768)
    const float* lw  = (const float*)d_in[6];  // (2,1,256)
    const float* lb  = (const float*)d_in[7];  // (2,1)
    float* out = (float*)d_out;

    float* ws = (float*)d_ws;
    float* GI = ws;                                   // 18432*768 f32
    u64t* XH1 = (u64t*)(GI + (size_t)18432 * 768);    // 48*512
    u64t* XH2 = XH1 + 24576;
    u64t* PD1 = XH2 + 24576;                          // 48*4
    u64t* PD2 = PD1 + 192;
    u64t* Y1X = PD2 + 192;                            // 48*16*256
    u64t* GI2X = Y1X + 196608;                        // 48*16*768
    unsigned int* BPROG = (unsigned int*)(GI2X + 589824);  // 48*2
    unsigned int* CPROG = BPROG + 96;                      // 48*2

    float* OUTy = out;                                // (384,48,256)
    float* HS   = out + (size_t)18432 * 256;          // (2,48,256)
    float* TU   = HS + 2 * 48 * 256;                  // (48, 768)

    // zero all tags/progress each launch (graph-replay safe)
    hipMemsetAsync(XH1, 0, (size_t)835968 * sizeof(u64t) + 768, stream);

    dim3 ggrid(12, 144), gblk(256);
    gemm_nt<<<ggrid, gblk, 0, stream>>>(x, wih, bih, GI);
    fused_pipe<<<240, 512, 0, stream>>>(GI,
        wih + 196608, bih + 768,
        whh, bhh, whh + 196608, bhh + 768,
        lw, lb, lw + 256, lb + 1,
        hid, hid + 256,
        XH1, PD1, XH2, PD2, Y1X, GI2X, BPROG, CPROG,
        OUTy, HS, TU);
}

// Round 12
// 1998.155 us; speedup vs baseline: 1.1258x; 1.1258x over previous
//
#include <hip/hip_runtime.h>
#include <stdint.h>

// SkipGRU: T=384, B=48, C=H=256, L=2.
// r12 = r10 fused cross-layer pipeline (best verified, 1986us) + ONE change:
// s_sleep(1) backoff in the LONG-WAIT retry loops (C's gi2 polls, B's y1
// poll, backpressure loops). r10/r11 evidence: the fused kernel carries
// ~110MB of excess FETCH from spin-polls -- back-to-back dependent
// agent-scope loads from up to 144 WGs hammering the device coherence path
// that also services A's publishes and every pair exchange. VALUBusy 20.5%
// at 208 WGs reads as overlapped-but-uniformly-slow, i.e. a congested shared
// resource, not a chained pipeline. Backoff cuts poll traffic several-fold
// at <= one sleep quantum (~64cy) of wake latency. Pair polls (XH/PD) stay
// untouched -- their spin timing is load-bearing (r5-r9 lessons).
//
// Roles: A(96)=layer-1 rec pairs (r9 structure + y1 ring publish, no Y0);
// B(16)=gi2 producers (half W_ih2 in 192 regs, 6 batches each); C(96)=
// layer-2 rec pairs (gi2 from 16-deep tagged ring), writes OUTy/HS/TU.
// Deadlock-freedom: 208 blocks <= 256 CUs -> all resident; mutual waits only
// within pairs (r2-verified tagged protocol); A->B->C forward-only; ring
// reuse guarded by progress counters (D=16), acyclic. Tags zeroed per launch.
// Kept lessons: A's mid-phase-2 GI1 HBM loads (pacing, r8/r9), plain
// __syncthreads (r6), compiler-tracked polls (r5), no extra register state
// (r4), NO C-side pacing loads (r11: pure cost, didn't cut retries).

#define T_STEPS 384
typedef unsigned long long u64t;

__device__ __forceinline__ float sigm_(float x) { return 1.f / (1.f + __expf(-x)); }
__device__ __forceinline__ float tanh_(float x) {
    float ax = fabsf(x);
    float e  = __expf(-2.f * ax);
    float r  = (1.f - e) / (1.f + e);
    return copysignf(r, x);
}

// ---------------------------------------------------------------------------
// GEMM1: O[m][n] = sum_k X[m][k]*W[n][k] + B[n]; M=18432, N=768, K=256.
// (unchanged)
// ---------------------------------------------------------------------------
__global__ __launch_bounds__(256, 2) void gemm_nt(const float* __restrict__ X,
                                                  const float* __restrict__ W,
                                                  const float* __restrict__ B,
                                                  float* __restrict__ O)
{
    __shared__ float As[32 * 140];
    __shared__ float Bs[32 * 68];

    const int tid = threadIdx.x;
    const int tx  = tid & 15;
    const int ty  = tid >> 4;
    const int n0  = blockIdx.x * 64;
    const int m0  = blockIdx.y * 128;

    float acc[8][4];
#pragma unroll
    for (int i = 0; i < 8; ++i)
#pragma unroll
        for (int j = 0; j < 4; ++j) acc[i][j] = 0.f;

    const float4 bias4 = *reinterpret_cast<const float4*>(B + n0 + tx * 4);

    for (int kc = 0; kc < 8; ++kc) {
        const int k0 = kc * 32;
        float4 a[4], bb[2];
#pragma unroll
        for (int j = 0; j < 4; ++j) {
            int f = tid + 256 * j, r = f >> 3, cq = f & 7;
            a[j] = *reinterpret_cast<const float4*>(X + (size_t)(m0 + r) * 256 + k0 + cq * 4);
        }
#pragma unroll
        for (int j = 0; j < 2; ++j) {
            int f = tid + 256 * j, r = f >> 3, cq = f & 7;
            bb[j] = *reinterpret_cast<const float4*>(W + (size_t)(n0 + r) * 256 + k0 + cq * 4);
        }
        __syncthreads();
#pragma unroll
        for (int j = 0; j < 4; ++j) {
            int f = tid + 256 * j, r = f >> 3, cq = f & 7;
            As[(cq * 4 + 0) * 140 + r] = a[j].x;
            As[(cq * 4 + 1) * 140 + r] = a[j].y;
            As[(cq * 4 + 2) * 140 + r] = a[j].z;
            As[(cq * 4 + 3) * 140 + r] = a[j].w;
        }
#pragma unroll
        for (int j = 0; j < 2; ++j) {
            int f = tid + 256 * j, r = f >> 3, cq = f & 7;
            Bs[(cq * 4 + 0) * 68 + r] = bb[j].x;
            Bs[(cq * 4 + 1) * 68 + r] = bb[j].y;
            Bs[(cq * 4 + 2) * 68 + r] = bb[j].z;
            Bs[(cq * 4 + 3) * 68 + r] = bb[j].w;
        }
        __syncthreads();
#pragma unroll 8
        for (int kk = 0; kk < 32; ++kk) {
            float4 av0 = *reinterpret_cast<const float4*>(As + kk * 140 + ty * 8);
            float4 av1 = *reinterpret_cast<const float4*>(As + kk * 140 + ty * 8 + 4);
            float4 bv  = *reinterpret_cast<const float4*>(Bs + kk * 68 + tx * 4);
            float am[8] = {av0.x, av0.y, av0.z, av0.w, av1.x, av1.y, av1.z, av1.w};
            float bn[4] = {bv.x, bv.y, bv.z, bv.w};
#pragma unroll
            for (int i = 0; i < 8; ++i)
#pragma unroll
                for (int j = 0; j < 4; ++j) acc[i][j] = fmaf(am[i], bn[j], acc[i][j]);
        }
    }
#pragma unroll
    for (int i = 0; i < 8; ++i) {
        int row = m0 + ty * 8 + i;
        float4 o;
        o.x = acc[i][0] + bias4.x;
        o.y = acc[i][1] + bias4.y;
        o.z = acc[i][2] + bias4.z;
        o.w = acc[i][3] + bias4.w;
        *reinterpret_cast<float4*>(O + (size_t)row * 768 + n0 + tx * 4) = o;
    }
}

// ---------------------------------------------------------------------------
__global__ __launch_bounds__(512, 2) void fused_pipe(
    const float* __restrict__ GI1,
    const float* __restrict__ wih2, const float* __restrict__ bih2,
    const float* __restrict__ whh1, const float* __restrict__ bhh1,
    const float* __restrict__ whh2, const float* __restrict__ bhh2,
    const float* __restrict__ lw1, const float* __restrict__ lb1,
    const float* __restrict__ lw2, const float* __restrict__ lb2,
    const float* __restrict__ hid1, const float* __restrict__ hid2,
    u64t* XH1, u64t* PD1, u64t* XH2, u64t* PD2,
    u64t* Y1X, u64t* GI2X, unsigned int* BPROG, unsigned int* CPROG,
    float* __restrict__ OUTy, float* __restrict__ HS, float* __restrict__ TU)
{
    __shared__ float hbuf[2112];   // A/C: 2 parities x 4 copies x 264
    __shared__ float pdw[2][8];
    __shared__ float ybuf[6336];   // B: 6 batches x (4 copies x 264)

    const int tid  = threadIdx.x;
    const int lane = tid & 63;
    const int w    = tid >> 6;
    const int g    = lane & 15;
    const int s    = lane >> 4;
    const int blk  = blockIdx.x;

    if (blk < 192) {
        // ================= roles A (blk<96) and C (96..191): rec pair ======
        const bool isA = (blk < 96);
        const int rb   = isA ? blk : (blk - 96);
        const int b    = rb % 48;
        const int p    = rb / 48;
        const int q    = 1 - p;
        const int cb   = w * 16 + g;
        const int c    = p * 128 + cb;

        const float* whh = isA ? whh1 : whh2;
        const float* bhh = isA ? bhh1 : bhh2;
        const float* lwl = isA ? lw1 : lw2;
        const float* lbl = isA ? lb1 : lb2;
        const float* hid = isA ? hid1 : hid2;
        u64t* XHb = (isA ? XH1 : XH2) + b * 512;
        u64t* PDb = (isA ? PD1 : PD2) + b * 4;

        float4 WrO[8], WzO[8], WnO[8], WrP[8], WzP[8], WnP[8];
        {
            const size_t rR = (size_t)c * 256;
            const size_t rZ = (size_t)(256 + c) * 256;
            const size_t rN = (size_t)(512 + c) * 256;
            const int ko = p * 128 + s * 32;
            const int kq = q * 128 + s * 32;
            const float4* a  = reinterpret_cast<const float4*>(whh + rR + ko);
            const float4* bv = reinterpret_cast<const float4*>(whh + rZ + ko);
            const float4* cv = reinterpret_cast<const float4*>(whh + rN + ko);
            const float4* d4 = reinterpret_cast<const float4*>(whh + rR + kq);
            const float4* e4 = reinterpret_cast<const float4*>(whh + rZ + kq);
            const float4* f4 = reinterpret_cast<const float4*>(whh + rN + kq);
#pragma unroll
            for (int i = 0; i < 8; ++i) {
                WrO[i] = a[i];  WzO[i] = bv[i]; WnO[i] = cv[i];
                WrP[i] = d4[i]; WzP[i] = e4[i]; WnP[i] = f4[i];
            }
        }
        const float bhr = bhh[c], bhz = bhh[256 + c], bhn = bhh[512 + c];
        const float lwc = lwl[c];
        const float lbv = lbl[0];

        if (tid < 256) {
            float v = hid[tid];
            hbuf[tid] = v; hbuf[264 + tid] = v; hbuf[528 + tid] = v; hbuf[792 + tid] = v;
        }
        __syncthreads();

        // gi(0): A reads GEMM1 output; C issues ring polls (checked at t=0 top)
        float gir = 0.f, giz = 0.f, gin = 0.f;
        u64t pkr = 0, pkz = 0, pkn = 0;
        if (isA) {
            const size_t g0 = (size_t)b * 768 + c;
            gir = GI1[g0]; giz = GI1[g0 + 256]; gin = GI1[g0 + 512];
        } else {
            const u64t* g0 = GI2X + ((size_t)b * 16) * 768 + c;
            pkr = __hip_atomic_load(g0,       __ATOMIC_RELAXED, __HIP_MEMORY_SCOPE_AGENT);
            pkz = __hip_atomic_load(g0 + 256, __ATOMIC_RELAXED, __HIP_MEMORY_SCOPE_AGENT);
            pkn = __hip_atomic_load(g0 + 512, __ATOMIC_RELAXED, __HIP_MEMORY_SCOPE_AGENT);
        }

        float sAr, sAz, sAn;
        {
            float ar = 0.f, az = 0.f, an = 0.f;
            const float4* ho = reinterpret_cast<const float4*>(hbuf + s * 264 + p * 128 + s * 32);
            const float4* hq = reinterpret_cast<const float4*>(hbuf + s * 264 + q * 128 + s * 32);
#pragma unroll
            for (int i = 0; i < 8; ++i) {
                float4 hv = ho[i];
                ar = fmaf(WrO[i].x, hv.x, ar); ar = fmaf(WrO[i].y, hv.y, ar);
                ar = fmaf(WrO[i].z, hv.z, ar); ar = fmaf(WrO[i].w, hv.w, ar);
                az = fmaf(WzO[i].x, hv.x, az); az = fmaf(WzO[i].y, hv.y, az);
                az = fmaf(WzO[i].z, hv.z, az); az = fmaf(WzO[i].w, hv.w, az);
                an = fmaf(WnO[i].x, hv.x, an); an = fmaf(WnO[i].y, hv.y, an);
                an = fmaf(WnO[i].z, hv.z, an); an = fmaf(WnO[i].w, hv.w, an);
            }
#pragma unroll
            for (int i = 0; i < 8; ++i) {
                float4 hv = hq[i];
                ar = fmaf(WrP[i].x, hv.x, ar); ar = fmaf(WrP[i].y, hv.y, ar);
                ar = fmaf(WrP[i].z, hv.z, ar); ar = fmaf(WrP[i].w, hv.w, ar);
                az = fmaf(WzP[i].x, hv.x, az); az = fmaf(WzP[i].y, hv.y, az);
                az = fmaf(WzP[i].z, hv.z, az); az = fmaf(WzP[i].w, hv.w, az);
                an = fmaf(WnP[i].x, hv.x, an); an = fmaf(WnP[i].y, hv.y, an);
                an = fmaf(WnP[i].z, hv.z, an); an = fmaf(WnP[i].w, hv.w, an);
            }
            ar += __shfl_xor(ar, 16); ar += __shfl_xor(ar, 32);
            az += __shfl_xor(az, 16); az += __shfl_xor(az, 32);
            an += __shfl_xor(an, 16); an += __shfl_xor(an, 32);
            sAr = ar; sAz = az; sAn = an;
        }

        float* hsout = isA ? HS : (HS + 12288);
        float* tubase = TU + (isA ? 0 : 384);
        u64t*  Y1b = Y1X + (size_t)b * 16 * 256;

        float u = 1.f, d = 0.f;
        bool  skip = false;
        int   ns = 0, hp = 0, bcap = 16;

        for (int t = 0; t < T_STEPS; ++t) {
            const float bu  = rintf(u);        // jnp.round == RNE
            const float obu = 1.f - bu;
            const int tp = (t < T_STEPS - 1) ? t + 1 : t;
            const size_t gpb = ((size_t)tp * 48 + b) * 768 + c;   // A only
            const u64t* gnext = GI2X + ((size_t)b * 16 + (tp & 15)) * 768 + c; // C only
            const size_t yrow = ((size_t)t * 48 + b) * 256;

            // A: ring backpressure vs B (uniform; rare refresh; backoff)
            if (isA && t >= bcap) {
                unsigned int m;
                do {
                    unsigned int p0 = __hip_atomic_load(BPROG + b * 2,     __ATOMIC_RELAXED, __HIP_MEMORY_SCOPE_AGENT);
                    unsigned int p1 = __hip_atomic_load(BPROG + b * 2 + 1, __ATOMIC_RELAXED, __HIP_MEMORY_SCOPE_AGENT);
                    m = p0 < p1 ? p0 : p1;
                    if ((int)m < t - 15) __builtin_amdgcn_s_sleep(1);
                } while ((int)m < t - 15);
                bcap = (int)m + 16;
            }
            u64t* yslot = Y1b + (size_t)(t & 15) * 256;

            if (skip) {
                float* hb = hbuf + hp * 1056;
                float hcv = hb[s * 264 + c];
                float nh  = hcv * obu;
                if (bu != 0.f) hb[s * 264 + c] = nh;
                if (s == 0) {
                    if (isA) {
                        u64t pk = ((u64t)(unsigned)(t + 1) << 32) | (u64t)__float_as_uint(nh);
                        __hip_atomic_store(yslot + c, pk, __ATOMIC_RELAXED, __HIP_MEMORY_SCOPE_AGENT);
                    }
                } else if (s == 1) {
                    if (!isA) OUTy[yrow + c] = nh;
                    if (t == T_STEPS - 1) hsout[b * 256 + c] = nh;
                }
                if (bu != 0.f) { sAr = 0.f; sAz = 0.f; sAn = 0.f; }
                if (p == 0 && tid == 0) tubase[b * 768 + t] = bu;
                if (!isA && tid == 0)
                    __hip_atomic_store(CPROG + b * 2 + p, (unsigned)(t + 1), __ATOMIC_RELAXED, __HIP_MEMORY_SCOPE_AGENT);
                float pr = 0.f, pz = 0.f, pn = 0.f;
                if (isA) { pr = GI1[gpb]; pz = GI1[gpb + 256]; pn = GI1[gpb + 512]; }
                else {
                    pkr = __hip_atomic_load(gnext,       __ATOMIC_RELAXED, __HIP_MEMORY_SCOPE_AGENT);
                    pkz = __hip_atomic_load(gnext + 256, __ATOMIC_RELAXED, __HIP_MEMORY_SCOPE_AGENT);
                    pkn = __hip_atomic_load(gnext + 512, __ATOMIC_RELAXED, __HIP_MEMORY_SCOPE_AGENT);
                }
                u    = fminf(fmaxf(u + d, 0.f), 1.f) * obu;
                skip = (u < 0.5f);
                __syncthreads();
                if (isA) { gir = pr; giz = pz; gin = pn; }
            } else {
                const int sl = ns & 1;
                const unsigned int tag = (unsigned)ns + 1u;

                if (!isA) {
                    // complete gi2(t) polls; REAL wait on B -> sleep backoff
                    const u64t* gcur = GI2X + ((size_t)b * 16 + (t & 15)) * 768 + c;
                    const unsigned int wt = (unsigned)(t + 1);
                    while ((unsigned)(pkr >> 32) < wt) {
                        __builtin_amdgcn_s_sleep(1);
                        pkr = __hip_atomic_load(gcur,       __ATOMIC_RELAXED, __HIP_MEMORY_SCOPE_AGENT);
                    }
                    while ((unsigned)(pkz >> 32) < wt) {
                        __builtin_amdgcn_s_sleep(1);
                        pkz = __hip_atomic_load(gcur + 256, __ATOMIC_RELAXED, __HIP_MEMORY_SCOPE_AGENT);
                    }
                    while ((unsigned)(pkn >> 32) < wt) {
                        __builtin_amdgcn_s_sleep(1);
                        pkn = __hip_atomic_load(gcur + 512, __ATOMIC_RELAXED, __HIP_MEMORY_SCOPE_AGENT);
                    }
                    gir = __uint_as_float((unsigned)pkr);
                    giz = __uint_as_float((unsigned)pkz);
                    gin = __uint_as_float((unsigned)pkn);
                }

                float hcv = hbuf[hp * 1056 + s * 264 + c];
                float rr  = sigm_(gir + sAr + bhr);
                float zz  = sigm_(giz + sAz + bhz);
                float tn  = tanh_(gin + rr * (sAn + bhn));
                float nh  = ((1.f - zz) * tn + zz * hcv) * bu;
                float pdv = nh * lwc;

                float* hbn = hbuf + (hp ^ 1) * 1056;
                hbn[s * 264 + c] = nh;
                if (s == 0) {
                    u64t pkx = ((u64t)tag << 32) | (u64t)__float_as_uint(nh);
                    __hip_atomic_store(XHb + sl * 256 + c, pkx, __ATOMIC_RELAXED, __HIP_MEMORY_SCOPE_AGENT);
                    if (isA) {
                        u64t pky = ((u64t)(unsigned)(t + 1) << 32) | (u64t)__float_as_uint(nh);
                        __hip_atomic_store(yslot + c, pky, __ATOMIC_RELAXED, __HIP_MEMORY_SCOPE_AGENT);
                    }
                } else if (s == 1) {
                    if (!isA) OUTy[yrow + c] = nh;
                    if (t == T_STEPS - 1) hsout[b * 256 + c] = nh;
                }
                pdv += __shfl_xor(pdv, 1);  pdv += __shfl_xor(pdv, 2);  pdv += __shfl_xor(pdv, 4);
                pdv += __shfl_xor(pdv, 8);  pdv += __shfl_xor(pdv, 16); pdv += __shfl_xor(pdv, 32);
                pdv *= 0.25f;
                if (lane == 0) pdw[sl][w] = pdv;
                if (p == 0 && tid == 0) tubase[b * 768 + t] = bu;
                if (!isA && tid == 0)
                    __hip_atomic_store(CPROG + b * 2 + p, (unsigned)(t + 1), __ATOMIC_RELAXED, __HIP_MEMORY_SCOPE_AGENT);
                __syncthreads();  // B1

                float ownpd = ((pdw[sl][0] + pdw[sl][1]) + (pdw[sl][2] + pdw[sl][3]))
                            + ((pdw[sl][4] + pdw[sl][5]) + (pdw[sl][6] + pdw[sl][7]));
                if (tid == 0) {
                    u64t pkp = ((u64t)tag << 32) | (u64t)__float_as_uint(ownpd);
                    __hip_atomic_store(PDb + sl * 2 + p, pkp, __ATOMIC_RELAXED, __HIP_MEMORY_SCOPE_AGENT);
                }
                u64t pk0 = __hip_atomic_load(XHb + sl * 256 + q * 128 + cb, __ATOMIC_RELAXED, __HIP_MEMORY_SCOPE_AGENT);
                // mid-phase-2 prefetch slot (pacing position, r8 lesson)
                float pr = 0.f, pz = 0.f, pn = 0.f;
                if (isA) { pr = GI1[gpb]; pz = GI1[gpb + 256]; pn = GI1[gpb + 512]; }
                else {
                    pkr = __hip_atomic_load(gnext,       __ATOMIC_RELAXED, __HIP_MEMORY_SCOPE_AGENT);
                    pkz = __hip_atomic_load(gnext + 256, __ATOMIC_RELAXED, __HIP_MEMORY_SCOPE_AGENT);
                    pkn = __hip_atomic_load(gnext + 512, __ATOMIC_RELAXED, __HIP_MEMORY_SCOPE_AGENT);
                }

                float ar = 0.f, az = 0.f, an = 0.f;
                {
                    const float4* ho = reinterpret_cast<const float4*>(hbn + s * 264 + p * 128 + s * 32);
#pragma unroll
                    for (int i = 0; i < 8; ++i) {
                        float4 hv = ho[i];
                        ar = fmaf(WrO[i].x, hv.x, ar); ar = fmaf(WrO[i].y, hv.y, ar);
                        ar = fmaf(WrO[i].z, hv.z, ar); ar = fmaf(WrO[i].w, hv.w, ar);
                        az = fmaf(WzO[i].x, hv.x, az); az = fmaf(WzO[i].y, hv.y, az);
                        az = fmaf(WzO[i].z, hv.z, az); az = fmaf(WzO[i].w, hv.w, az);
                        an = fmaf(WnO[i].x, hv.x, an); an = fmaf(WnO[i].y, hv.y, an);
                        an = fmaf(WnO[i].z, hv.z, an); an = fmaf(WnO[i].w, hv.w, an);
                    }
                }
                {
                    const int qc = q * 128 + cb;
                    const u64t* slp = XHb + sl * 256 + qc;
                    while ((unsigned)(pk0 >> 32) < tag)
                        pk0 = __hip_atomic_load(slp, __ATOMIC_RELAXED, __HIP_MEMORY_SCOPE_AGENT);
                    hbn[s * 264 + qc] = __uint_as_float((unsigned)pk0);
                }
                __syncthreads();  // B2

                u64t pkq = __hip_atomic_load(PDb + sl * 2 + q, __ATOMIC_RELAXED, __HIP_MEMORY_SCOPE_AGENT);
                {
                    const float4* hq = reinterpret_cast<const float4*>(hbn + s * 264 + q * 128 + s * 32);
#pragma unroll
                    for (int i = 0; i < 8; ++i) {
                        float4 hv = hq[i];
                        ar = fmaf(WrP[i].x, hv.x, ar); ar = fmaf(WrP[i].y, hv.y, ar);
                        ar = fmaf(WrP[i].z, hv.z, ar); ar = fmaf(WrP[i].w, hv.w, ar);
                        az = fmaf(WzP[i].x, hv.x, az); az = fmaf(WzP[i].y, hv.y, az);
                        az = fmaf(WzP[i].z, hv.z, az); az = fmaf(WzP[i].w, hv.w, az);
                        an = fmaf(WnP[i].x, hv.x, an); an = fmaf(WnP[i].y, hv.y, an);
                        an = fmaf(WnP[i].z, hv.z, an); an = fmaf(WnP[i].w, hv.w, an);
                    }
                }
                ar += __shfl_xor(ar, 16); ar += __shfl_xor(ar, 32);
                az += __shfl_xor(az, 16); az += __shfl_xor(az, 32);
                an += __shfl_xor(an, 16); an += __shfl_xor(an, 32);
                sAr = ar; sAz = az; sAn = an;

                while ((unsigned)(pkq >> 32) < tag)
                    pkq = __hip_atomic_load(PDb + sl * 2 + q, __ATOMIC_RELAXED, __HIP_MEMORY_SCOPE_AGENT);
                const float pdq = __uint_as_float((unsigned)pkq);

                float dns = sigm_((ownpd + pdq) + lbv);  // commutative -> lockstep
                u = dns * bu; d = dns;
                skip = (u < 0.5f);
                ns++; hp ^= 1;
                if (isA) { gir = pr; giz = pz; gin = pn; }
            }
        }
    } else {
        // ================= role B: gi2 producer ============================
        const int j   = blk - 192;       // 0..15
        const int hf  = j & 1;
        const int b0  = (j >> 1) * 6;    // 6 batches per WG
        const int cb2 = w * 16 + g;
        const int c2  = hf * 128 + cb2;

        float4 Wr[16], Wz[16], Wn[16];
        {
            const float4* r4 = reinterpret_cast<const float4*>(wih2 + (size_t)c2 * 256 + s * 64);
            const float4* z4 = reinterpret_cast<const float4*>(wih2 + (size_t)(256 + c2) * 256 + s * 64);
            const float4* n4 = reinterpret_cast<const float4*>(wih2 + (size_t)(512 + c2) * 256 + s * 64);
#pragma unroll
            for (int i = 0; i < 16; ++i) { Wr[i] = r4[i]; Wz[i] = z4[i]; Wn[i] = n4[i]; }
        }
        const float bR = bih2[c2], bZ = bih2[256 + c2], bN = bih2[512 + c2];

        int ccap[6];
#pragma unroll
        for (int i = 0; i < 6; ++i) ccap[i] = 16;

        const int i0 = tid, i1 = tid + 512, i2 = tid + 1024;
        const int bb0 = i0 >> 8, co0 = i0 & 255;
        const int bb1 = i1 >> 8, co1 = i1 & 255;
        const int bb2 = i2 >> 8, co2 = i2 & 255;

        for (int t = 0; t < T_STEPS; ++t) {
            const int slot = t & 15;
            const unsigned int wt = (unsigned)(t + 1);
            const u64t* a0 = Y1X + ((size_t)(b0 + bb0) * 16 + slot) * 256 + co0;
            const u64t* a1 = Y1X + ((size_t)(b0 + bb1) * 16 + slot) * 256 + co1;
            const u64t* a2 = Y1X + ((size_t)(b0 + bb2) * 16 + slot) * 256 + co2;
            u64t v0 = __hip_atomic_load(a0, __ATOMIC_RELAXED, __HIP_MEMORY_SCOPE_AGENT);
            u64t v1 = __hip_atomic_load(a1, __ATOMIC_RELAXED, __HIP_MEMORY_SCOPE_AGENT);
            u64t v2 = __hip_atomic_load(a2, __ATOMIC_RELAXED, __HIP_MEMORY_SCOPE_AGENT);
            // REAL wait on A -> sleep backoff
            while ((unsigned)(v0 >> 32) < wt) {
                __builtin_amdgcn_s_sleep(1);
                v0 = __hip_atomic_load(a0, __ATOMIC_RELAXED, __HIP_MEMORY_SCOPE_AGENT);
            }
            while ((unsigned)(v1 >> 32) < wt) {
                __builtin_amdgcn_s_sleep(1);
                v1 = __hip_atomic_load(a1, __ATOMIC_RELAXED, __HIP_MEMORY_SCOPE_AGENT);
            }
            while ((unsigned)(v2 >> 32) < wt) {
                __builtin_amdgcn_s_sleep(1);
                v2 = __hip_atomic_load(a2, __ATOMIC_RELAXED, __HIP_MEMORY_SCOPE_AGENT);
            }
            {
                float v = __uint_as_float((unsigned)v0); float* yb = ybuf + bb0 * 1056;
                yb[co0] = v; yb[264 + co0] = v; yb[528 + co0] = v; yb[792 + co0] = v;
            }
            {
                float v = __uint_as_float((unsigned)v1); float* yb = ybuf + bb1 * 1056;
                yb[co1] = v; yb[264 + co1] = v; yb[528 + co1] = v; yb[792 + co1] = v;
            }
            {
                float v = __uint_as_float((unsigned)v2); float* yb = ybuf + bb2 * 1056;
                yb[co2] = v; yb[264 + co2] = v; yb[528 + co2] = v; yb[792 + co2] = v;
            }
            __syncthreads();
            if (tid < 6)
                __hip_atomic_store(BPROG + (b0 + tid) * 2 + hf, wt, __ATOMIC_RELAXED, __HIP_MEMORY_SCOPE_AGENT);
#pragma unroll
            for (int bb = 0; bb < 6; ++bb) {
                if (t >= ccap[bb]) {   // ring backpressure vs C (rare; backoff)
                    unsigned int m;
                    do {
                        m = __hip_atomic_load(CPROG + (b0 + bb) * 2 + hf, __ATOMIC_RELAXED, __HIP_MEMORY_SCOPE_AGENT);
                        if ((int)m < t - 15) __builtin_amdgcn_s_sleep(1);
                    } while ((int)m < t - 15);
                    ccap[bb] = (int)m + 16;
                }
                float ar = 0.f, az = 0.f, an = 0.f;
                const float4* yv = reinterpret_cast<const float4*>(ybuf + bb * 1056 + s * 328);
#pragma unroll
                for (int i = 0; i < 16; ++i) {
                    float4 hv = yv[i];
                    ar = fmaf(Wr[i].x, hv.x, ar); ar = fmaf(Wr[i].y, hv.y, ar);
                    ar = fmaf(Wr[i].z, hv.z, ar); ar = fmaf(Wr[i].w, hv.w, ar);
                    az = fmaf(Wz[i].x, hv.x, az); az = fmaf(Wz[i].y, hv.y, az);
                    az = fmaf(Wz[i].z, hv.z, az); az = fmaf(Wz[i].w, hv.w, az);
                    an = fmaf(Wn[i].x, hv.x, an); an = fmaf(Wn[i].y, hv.y, an);
                    an = fmaf(Wn[i].z, hv.z, an); an = fmaf(Wn[i].w, hv.w, an);
                }
                ar += __shfl_xor(ar, 16); ar += __shfl_xor(ar, 32);
                az += __shfl_xor(az, 16); az += __shfl_xor(az, 32);
                an += __shfl_xor(an, 16); an += __shfl_xor(an, 32);
                ar += bR; az += bZ; an += bN;
                if (s < 3) {
                    float v = (s == 0) ? ar : ((s == 1) ? az : an);
                    u64t pk = ((u64t)wt << 32) | (u64t)__float_as_uint(v);
                    __hip_atomic_store(GI2X + ((size_t)(b0 + bb) * 16 + slot) * 768 + s * 256 + c2,
                                       pk, __ATOMIC_RELAXED, __HIP_MEMORY_SCOPE_AGENT);
                }
            }
            __syncthreads();  // ybuf reuse guard
        }
    }
}

// ---------------------------------------------------------------------------
extern "C" void kernel_launch(void* const* d_in, const int* in_sizes, int n_in,
                              void* d_out, int out_size, void* d_ws, size_t ws_size,
                              hipStream_t stream)
{
    const float* x   = (const float*)d_in[0];  // (384,48,256)
    const float* hid = (const float*)d_in[1];  // (2,1,256)
    const float* wih = (const float*)d_in[2];  // (2,768,256)
    const float* whh = (const float*)d_in[3];  // (2,768,256)
    const float* bih = (const float*)d_in[4];  // (2,768)
    const float* bhh = (const float*)d_in[5];  // (2,768)
    const float* lw  = (const float*)d_in[6];  // (2,1,256)
    const float* lb  = (const float*)d_in[7];  // (2,1)
    float* out = (float*)d_out;

    float* ws = (float*)d_ws;
    float* GI = ws;                                   // 18432*768 f32
    u64t* XH1 = (u64t*)(GI + (size_t)18432 * 768);    // 48*512
    u64t* XH2 = XH1 + 24576;
    u64t* PD1 = XH2 + 24576;                          // 48*4
    u64t* PD2 = PD1 + 192;
    u64t* Y1X = PD2 + 192;                            // 48*16*256
    u64t* GI2X = Y1X + 196608;                        // 48*16*768
    unsigned int* BPROG = (unsigned int*)(GI2X + 589824);  // 48*2
    unsigned int* CPROG = BPROG + 96;                      // 48*2

    float* OUTy = out;                                // (384,48,256)
    float* HS   = out + (size_t)18432 * 256;          // (2,48,256)
    float* TU   = HS + 2 * 48 * 256;                  // (48, 768)

    // zero all tags/progress each launch (graph-replay safe)
    hipMemsetAsync(XH1, 0, (size_t)835968 * sizeof(u64t) + 768, stream);

    dim3 ggrid(12, 144), gblk(256);
    gemm_nt<<<ggrid, gblk, 0, stream>>>(x, wih, bih, GI);
    fused_pipe<<<208, 512, 0, stream>>>(GI,
        wih + 196608, bih + 768,
        whh, bhh, whh + 196608, bhh + 768,
        lw, lb, lw + 256, lb + 1,
        hid, hid + 256,
        XH1, PD1, XH2, PD2, Y1X, GI2X, BPROG, CPROG,
        OUTy, HS, TU);
}